// Round 6
// baseline (558.470 us; speedup 1.0000x reference)
//
#include <hip/hip_runtime.h>
#include <cstdint>
#include <cstddef>

typedef _Float16 half8 __attribute__((ext_vector_type(8)));
typedef _Float16 half4 __attribute__((ext_vector_type(4)));
typedef float f32x4 __attribute__((ext_vector_type(4)));

// async global->LDS, 16B per lane; LDS dest must be wave-uniform base + lane*16
#define GLDS16(g, l) __builtin_amdgcn_global_load_lds( \
    (__attribute__((address_space(1))) void*)(g), \
    (__attribute__((address_space(3))) void*)(l), 16, 0, 0)

#define FENCE() asm volatile("" ::: "memory")
#define WAITV(n) asm volatile("s_waitcnt vmcnt(" #n ")" ::: "memory")

// ---------------------------------------------------------------------------
// fp32 -> fp16 convert
// ---------------------------------------------------------------------------
__global__ __launch_bounds__(256) void cvt_f32_f16(const float* __restrict__ src,
                                                   _Float16* __restrict__ dst, int n) {
  int i = (blockIdx.x * 256 + threadIdx.x) * 8;
  if (i >= n) return;
  float4 a = *(const float4*)(src + i);
  float4 b = *(const float4*)(src + i + 4);
  half8 h;
  h[0] = (_Float16)a.x; h[1] = (_Float16)a.y; h[2] = (_Float16)a.z; h[3] = (_Float16)a.w;
  h[4] = (_Float16)b.x; h[5] = (_Float16)b.y; h[6] = (_Float16)b.z; h[7] = (_Float16)b.w;
  *(half8*)(dst + i) = h;
}

// ---------------------------------------------------------------------------
// Persistent-A GEMM.  C[m,n] = sum_k A[m,k]*Bw[n,k] (+bias).  K=512.
// Block = 128-row A-band RESIDENT in LDS (128 KB, loaded once), sweeping all
// NOUT in 128-col B-tiles (NBX of them), B double-buffered 2x8 KB, BK=32.
// 512 thr, 8 waves (2M x 4N), wave tile 64x32, acc per bx = f32x4[4][2].
// Grid = 512 blocks = exactly 2 generations at 1 block/CU.
//
// Why: K=512 gives only 8-16 K-iters/block in classic tiling; per-block fixed
// cost (prologue fill + staged epilogue) rivals the work => every schedule
// pinned at 150-170 us (R1-R5).  Here one block runs NBX*16 iters (192 for
// QKV) against ONE prologue, and the epilogue is reg->global direct, spread
// 3 stores/iter inside the vmcnt ledger so it never forces a drain.
//
// LDS fragment order (slot = c*16+r in each 16-row band): glds writes and
// ds_read_b128 are both base + lane*16.
//   As[8 band][16 kt][4 c][16 r][8 h]   (131072 B)
//   Bs[2][8 band][4 c][16 r][8 h]       (2 x 8192 B)
//
// vmcnt ledger (per wave; all VMEM issue is uniform across threads):
//   iter (bx,kt): issue stage(g+1) [1 load]; wait stage(g); barrier;
//   ds_read As(kt)+Bs[kt&1]; 8 MFMA; barrier; issue 3 stores of accP (kt<=10).
//   After-set of stage(g): {stage(g+1)} + {3 stores if 1<=kt<=11 && bx>0}
//   => V = 4 in that window, else 1; last iter V = 0.
//   Store drain (3x2B/thread/iter ~ 3 KB/CU) < HBM share (~4.5 KB/iter): the
//   queue never backs up, so V=1 waits don't stall on stores.
// ---------------------------------------------------------------------------
template<int NOUT, int NBX, bool BIAS>
__global__ __launch_bounds__(512, 1) void gemm_pa(const _Float16* __restrict__ A,
                                                  const _Float16* __restrict__ Bw,
                                                  const float* __restrict__ bias,
                                                  void* __restrict__ Cout) {
  constexpr int K = 512;
  __shared__ _Float16 As[65536];     // 128 KB persistent A-band
  __shared__ _Float16 Bs[2][4096];   // 2 x 8 KB B-tile dbuf
  __shared__ float BiasL[BIAS ? 512 : 4];

  const int t    = threadIdx.x;      // 0..511
  const int lane = t & 63;
  const int wid  = t >> 6;           // 0..7
  const int wm   = wid >> 2;         // M half: rows wm*64..+63
  const int wn   = wid & 3;          // N quarter: cols wn*32..+31
  const int cl   = lane & 15, q = lane >> 4;
  const int m_base = blockIdx.x * 128;

  // B staging: slot t -> band b=t>>6, chunk c=(t>>4)&3, row r=t&15
  const _Float16* bRow = Bw + (size_t)(((t >> 6) << 4) | (t & 15)) * K + ((t >> 4) & 3) * 8;

  if constexpr (BIAS) {
    float4 bv = *(const float4*)(bias + (t & 127) * 4);   // uniform VMEM count
    if (t < 128) *(float4*)&BiasL[t * 4] = bv;            // lgkm only
  }

  // ---- prologue: fill A-band (16 glds/thread) + stage B(bx0,kt0) ----
#pragma unroll
  for (int i = 0; i < 16; ++i) {
    const int s = t + i * 512;      // r=s&15, c=(s>>4)&3, kt=(s>>6)&15, b=s>>10
    const int r = s & 15, c = (s >> 4) & 3, kt = (s >> 6) & 15, b = s >> 10;
    GLDS16(A + (size_t)(m_base + b * 16 + r) * K + kt * 32 + c * 8, (char*)As + s * 16);
  }
  GLDS16(bRow, (char*)&Bs[0][0] + t * 16);
  FENCE();

  f32x4 accC[4][2] = {};
  f32x4 accP[4][2] = {};
  float biasP0 = 0.f, biasP1 = 0.f;

  const int rowb = m_base + wm * 64 + q * 4;   // + mt*16 + r
  const int colb = wn * 32 + cl;               // + bx*128 + fn*16

  for (int bx = 0; bx < NBX; ++bx) {
#pragma unroll
    for (int kt = 0; kt < 16; ++kt) {
      // ---- stage(g+1) into Bs[(kt+1)&1] ----
      if (kt < 15) {
        GLDS16(bRow + (size_t)bx * 128 * K + (kt + 1) * 32,
               (char*)&Bs[(kt + 1) & 1][0] + t * 16);
      } else if (bx < NBX - 1) {
        GLDS16(bRow + (size_t)(bx + 1) * 128 * K,
               (char*)&Bs[0][0] + t * 16);
      }
      FENCE();
      // ---- wait stage(g); counted so stores/next-stage stay in flight ----
      if (kt == 15) {
        if (bx == NBX - 1) { WAITV(0); } else { WAITV(1); }
      } else if (kt >= 1 && kt <= 11) {
        if (bx > 0) { WAITV(4); } else { WAITV(1); }
      } else {
        WAITV(1);
      }
      __builtin_amdgcn_s_barrier();
      FENCE();

      // ---- ds_read fragments + MFMA ----
      half8 af[4], bf[2];
#pragma unroll
      for (int mt = 0; mt < 4; ++mt)
        af[mt] = *(const half8*)((const char*)As + (wm * 4 + mt) * 16384 + kt * 1024 + lane * 16);
#pragma unroll
      for (int fn = 0; fn < 2; ++fn)
        bf[fn] = *(const half8*)((const char*)&Bs[kt & 1][0] + (wn * 2 + fn) * 1024 + lane * 16);
      __builtin_amdgcn_s_setprio(1);
#pragma unroll
      for (int mt = 0; mt < 4; ++mt)
#pragma unroll
        for (int fn = 0; fn < 2; ++fn)
          accC[mt][fn] = __builtin_amdgcn_mfma_f32_16x16x32_f16(af[mt], bf[fn],
                                                                accC[mt][fn], 0, 0, 0);
      __builtin_amdgcn_s_setprio(0);
      __builtin_amdgcn_s_barrier();   // all reads of Bs[kt&1] done before re-stage
      FENCE();

      // ---- spread epilogue: 3 stores of accP (prev bx) per iter, kt 0..10 ----
      if (kt <= 10 && bx > 0) {
#pragma unroll
        for (int s2 = 0; s2 < 3; ++s2) {
          constexpr int base_j = 0;   // j computed statically below
          const int j = kt * 3 + s2;
          if (j < 32) {
            const int mt = j >> 3, fn = (j >> 2) & 1, r = j & 3;
            const size_t row = (size_t)(rowb + mt * 16 + r);
            const size_t col = (size_t)((bx - 1) * 128 + colb + fn * 16);
            float v = accP[mt][fn][r];
            if constexpr (BIAS) {
              v += (fn ? biasP1 : biasP0);
              ((float*)Cout)[row * NOUT + col] = v;
            } else {
              ((_Float16*)Cout)[row * NOUT + col] = (_Float16)v;
            }
          }
          (void)base_j;
        }
      }
      FENCE();
    }
    // ---- bx end: rotate acc, pick up bias for the tile just finished ----
    if (bx < NBX - 1) {
#pragma unroll
      for (int mt = 0; mt < 4; ++mt)
#pragma unroll
        for (int fn = 0; fn < 2; ++fn) {
          accP[mt][fn] = accC[mt][fn];
          accC[mt][fn] = f32x4{0.f, 0.f, 0.f, 0.f};
        }
      if constexpr (BIAS) {
        biasP0 = BiasL[bx * 128 + wn * 32 + cl];
        biasP1 = BiasL[bx * 128 + wn * 32 + 16 + cl];
      }
    }
  }

  // ---- final tile (bx = NBX-1) stored directly from accC ----
  float biasC0 = 0.f, biasC1 = 0.f;
  if constexpr (BIAS) {
    biasC0 = BiasL[(NBX - 1) * 128 + wn * 32 + cl];
    biasC1 = BiasL[(NBX - 1) * 128 + wn * 32 + 16 + cl];
  }
#pragma unroll
  for (int mt = 0; mt < 4; ++mt)
#pragma unroll
    for (int fn = 0; fn < 2; ++fn)
#pragma unroll
      for (int r = 0; r < 4; ++r) {
        const size_t row = (size_t)(rowb + mt * 16 + r);
        const size_t col = (size_t)((NBX - 1) * 128 + colb + fn * 16);
        float v = accC[mt][fn][r];
        if constexpr (BIAS) {
          v += (fn ? biasC1 : biasC0);
          ((float*)Cout)[row * NOUT + col] = v;
        } else {
          ((_Float16*)Cout)[row * NOUT + col] = (_Float16)v;
        }
      }
}

// ---------------------------------------------------------------------------
// Windowed attention (unchanged from R5): one block per (head h, window b).
// Q direct to registers; K glds fragment-order; V manual transpose; output
// staged through Os for coalesced 16B stores.  LDS 35.8 KB -> 4 blocks/CU.
// ---------------------------------------------------------------------------
__global__ __launch_bounds__(256, 4) void attn_win(const _Float16* __restrict__ QKV,
                                                   _Float16* __restrict__ Out) {
  __shared__ _Float16 Ks[4096];
  __shared__ _Float16 Vt[64][72];   // V transposed: Vt[e][j], padded rows
  __shared__ _Float16 Ps[64][72];   // softmax probs
  __shared__ _Float16 Os[64][72];   // output staging
  const int h = blockIdx.x, b = blockIdx.y;
  const int t = threadIdx.x;
  const int lane = t & 63, wid = t >> 6;
  const int cl = lane & 15, q = lane >> 4;
  const int m0 = wid * 16;          // wave's 16 query rows
  const int lane8 = lane * 8;

  // ---- stage K (async, fragment order) and V (manual transpose) ----
  {
    const int s0 = t, s1 = t + 256;
    const int r0 = ((s0 >> 7) << 4) | (s0 & 15), ch0 = (s0 >> 4) & 7;
    const int r1 = ((s1 >> 7) << 4) | (s1 & 15), ch1 = (s1 >> 4) & 7;
    const _Float16* g0 = QKV + (size_t)(b * 64 + r0) * 1536 + 512 + h * 64 + ch0 * 8;
    const _Float16* g1 = QKV + (size_t)(b * 64 + r1) * 1536 + 512 + h * 64 + ch1 * 8;
    GLDS16(g0, (char*)Ks + s0 * 16);
    GLDS16(g1, (char*)Ks + s1 * 16);

    const int vj = t & 63, vp = t >> 6;   // row j of V, 16-half chunk vp
    const _Float16* vsrc = QKV + (size_t)(b * 64 + vj) * 1536 + 1024 + h * 64 + vp * 16;
    half8 v0 = *(const half8*)vsrc;
    half8 v1 = *(const half8*)(vsrc + 8);
#pragma unroll
    for (int i = 0; i < 8; i++) Vt[vp * 16 + i][vj] = v0[i];
#pragma unroll
    for (int i = 0; i < 8; i++) Vt[vp * 16 + 8 + i][vj] = v1[i];
  }

  // ---- Q fragments direct to registers ----
  const _Float16* qsrc = QKV + (size_t)(b * 64 + m0 + cl) * 1536 + h * 64 + q * 8;
  half8 qa0 = *(const half8*)qsrc;          // k = 0..31 slice
  half8 qa1 = *(const half8*)(qsrc + 32);   // k = 32..63 slice

  __syncthreads();   // K staged (vmcnt drained) + Vt written

  // ---- S = Q K^T ----
  f32x4 s[4] = {};
#pragma unroll
  for (int nt = 0; nt < 4; nt++) {
    half8 b0 = *(const half8*)(Ks + nt * 1024 + lane8);
    half8 b1 = *(const half8*)(Ks + nt * 1024 + 512 + lane8);
    s[nt] = __builtin_amdgcn_mfma_f32_16x16x32_f16(qa0, b0, s[nt], 0, 0, 0);
    s[nt] = __builtin_amdgcn_mfma_f32_16x16x32_f16(qa1, b1, s[nt], 0, 0, 0);
  }

  // ---- softmax over 64 keys per row ----
  constexpr float SC = 0.125f * 1.44269504088896340736f;  // scale * log2(e)
#pragma unroll
  for (int r = 0; r < 4; r++) {
    float mx = fmaxf(fmaxf(s[0][r], s[1][r]), fmaxf(s[2][r], s[3][r]));
    mx = fmaxf(mx, __shfl_xor(mx, 1));
    mx = fmaxf(mx, __shfl_xor(mx, 2));
    mx = fmaxf(mx, __shfl_xor(mx, 4));
    mx = fmaxf(mx, __shfl_xor(mx, 8));
    float e[4], ssum = 0.f;
#pragma unroll
    for (int nt = 0; nt < 4; nt++) { e[nt] = exp2f((s[nt][r] - mx) * SC); ssum += e[nt]; }
    ssum += __shfl_xor(ssum, 1);
    ssum += __shfl_xor(ssum, 2);
    ssum += __shfl_xor(ssum, 4);
    ssum += __shfl_xor(ssum, 8);
    float inv = 1.f / ssum;
    const int row = m0 + q * 4 + r;
#pragma unroll
    for (int nt = 0; nt < 4; nt++) Ps[row][nt * 16 + cl] = (_Float16)(e[nt] * inv);
  }
  __syncthreads();

  // ---- O = P V ----
  f32x4 o[4] = {};
#pragma unroll
  for (int ks = 0; ks < 2; ks++) {
    half8 a = *(const half8*)&Ps[m0 + cl][ks * 32 + q * 8];
#pragma unroll
    for (int nt = 0; nt < 4; nt++) {
      half8 bb = *(const half8*)&Vt[nt * 16 + cl][ks * 32 + q * 8];
      o[nt] = __builtin_amdgcn_mfma_f32_16x16x32_f16(a, bb, o[nt], 0, 0, 0);
    }
  }
#pragma unroll
  for (int nt = 0; nt < 4; nt++)
#pragma unroll
    for (int r = 0; r < 4; r++)
      Os[m0 + q * 4 + r][nt * 16 + cl] = (_Float16)o[nt][r];
  __syncthreads();

  // ---- coalesced write-out ----
  {
    const int row = t >> 2, cs = t & 3;
    half8 h0 = *(const half8*)&Os[row][cs * 16];
    half8 h1 = *(const half8*)&Os[row][cs * 16 + 8];
    _Float16* dst = Out + (size_t)(b * 64 + row) * 512 + h * 64 + cs * 16;
    *(half8*)dst = h0;
    *((half8*)dst + 1) = h1;
  }
}

// ---------------------------------------------------------------------------
extern "C" void kernel_launch(void* const* d_in, const int* in_sizes, int n_in,
                              void* d_out, int out_size, void* d_ws, size_t ws_size,
                              hipStream_t stream) {
  const float* x      = (const float*)d_in[0];   // 16*4096*512
  const float* qkv_w  = (const float*)d_in[1];   // 1536*512
  const float* proj_w = (const float*)d_in[2];   // 512*512
  const float* proj_b = (const float*)d_in[3];   // 512
  float* out = (float*)d_out;

  char* ws = (char*)d_ws;
  _Float16* QKVh = (_Float16*)ws;                 // 65536*1536 fp16 = 201,326,592 B
  _Float16* Xh   = (_Float16*)(ws + 201326592);   // 65536*512 fp16 = 67,108,864 B
  _Float16* Outh = Xh;                            // alias: Xh dead after qkv_gemm
  _Float16* Wq   = (_Float16*)(ws + 268435456);   // 1536*512 fp16
  _Float16* Wp   = (_Float16*)(ws + 270008320);   // 512*512 fp16

  cvt_f32_f16<<<16384, 256, 0, stream>>>(x, Xh, 16 * 4096 * 512);
  cvt_f32_f16<<<384, 256, 0, stream>>>(qkv_w, Wq, 1536 * 512);
  cvt_f32_f16<<<128, 256, 0, stream>>>(proj_w, Wp, 512 * 512);
  gemm_pa<1536, 12, false><<<512, 512, 0, stream>>>(Xh, Wq, nullptr, QKVh);
  attn_win<<<dim3(8, 1024), 256, 0, stream>>>(QKVh, Outh);
  gemm_pa<512, 4, true><<<512, 512, 0, stream>>>(Outh, Wp, proj_b, out);
}